// Round 7
// baseline (368.501 us; speedup 1.0000x reference)
//
#include <hip/hip_runtime.h>
#include <hip/hip_fp16.h>
#include <stdint.h>

// Atten_L: B=2, L=64, C=256, S=256, D=512. fp32 I/O, fp16 MFMA compute.
// R7: T3-min 2-phase pipeline everywhere. R6 post-mortem: three different
// staging implementations all pinned at 149.6us / MfmaUtil 14 / HBM 18% ->
// the cost is the interval structure (stage -> vmcnt(0)+barrier -> compute
// exposes full load latency 8x/block), not the staging path. Fix per guide
// T3 minimum recipe: issue STAGE(t+1) BEFORE compute(t); single barrier per
// step after compute drains it -> latency hides under MFMA+ds_read.
//  - proj3: BK=32, A fp32 dbuf 2x16KB + B f16 dbuf 2x8KB = 48KB, 3 blk/CU.
//  - gemm_out: BK=32, 2x(8+8)KB = 32KB.
//  - attn_fused: QK^T As/Bs dbuf (96KB union w/ Ps+Vs, barrier-separated);
//    PV flattened to 16 (nc,kb) iters with kb-granular V dbuf (attn is
//    1 blk/CU -> intra-block overlap is its only latency hiding).

typedef _Float16 f16;
typedef __attribute__((ext_vector_type(8))) _Float16 f16x8;
typedef __attribute__((ext_vector_type(4))) _Float16 f16x4;
typedef __attribute__((ext_vector_type(4))) float f32x4;

__device__ __forceinline__ void glds16(const void* g, void* l)
{
    __builtin_amdgcn_global_load_lds(
        (const __attribute__((address_space(1))) void*)(uintptr_t)g,
        (__attribute__((address_space(3))) void*)(uint32_t)(uintptr_t)l,
        16, 0, 0);
}

// ---------------- merged q/k/v projection: 3072 blocks x 256 threads ------
// which = blockIdx>>10 selects (queries->qh), (keys->kh), (values->vT^T).
// BK=32, 2-phase dbuf. A staged as raw fp32 via glds16 (granule-rotation,
// 8x16B granules/row); B f16 (4x16B granules/row). cvt f32->f16 at frag read.
__global__ __launch_bounds__(256)
void proj3(const float* __restrict__ qin, const float* __restrict__ kin,
           const float* __restrict__ vin, const f16* __restrict__ wq,
           const f16* __restrict__ wkv, const float* __restrict__ bq,
           const float* __restrict__ bkv, f16* __restrict__ qh,
           f16* __restrict__ kh, f16* __restrict__ vT)
{
    __shared__ __align__(16) float Asf[2][128][32];   // 2 x 16 KB
    __shared__ __align__(16) f16  Bs[2][128][32];     // 2 x  8 KB

    const int p     = blockIdx.x;
    const int which = p >> 10;
    const int inner = p & 1023;
    const int xcd   = inner & 7;
    const int slot  = inner >> 3;
    const int m0 = (xcd + 8 * (slot >> 2)) * 128;
    const int n0 = (slot & 3) * 128;

    const float* A    = (which == 0) ? qin : (which == 1) ? kin : vin;
    const f16*   Bt   = (which == 0) ? wq : wkv;
    const float* bias = (which == 0) ? bq : bkv;

    const int tid  = threadIdx.x;
    const int lane = tid & 63;
    const int wave = tid >> 6;         // 0..3
    const int quad = lane >> 4;
    const int l16  = lane & 15;
    const int wr   = wave >> 1;        // 0..1 (64-row half)
    const int wc   = wave & 1;         // 0..1 (64-col half)

    f32x4 acc[4][4];
    #pragma unroll
    for (int i = 0; i < 4; ++i)
        #pragma unroll
        for (int j = 0; j < 4; ++j)
            acc[i][j] = (f32x4){0.f, 0.f, 0.f, 0.f};

    // A staging: row = 32 f32 = 8 granules x 16B; 8 rows/call; 16 calls.
    const int arow = lane >> 3;                    // 0..7 (row in call)
    const int ags  = ((lane & 7) - arow) & 7;      // pre-swizzled src granule
    // B staging: row = 32 f16 = 4 granules x 16B; 16 rows/call; 8 calls.
    const int brow = lane >> 2;                    // 0..15
    const int bgs  = ((lane & 3) - (brow & 3)) & 3;

    auto stage = [&](int b, int k0) {
        #pragma unroll
        for (int g = 0; g < 4; ++g) {
            const int R0 = (wave * 4 + g) * 8;
            glds16(A + (long)(m0 + R0 + arow) * 512 + k0 + ags * 4,
                   &Asf[b][R0][0]);
        }
        #pragma unroll
        for (int g = 0; g < 2; ++g) {
            const int R0 = (wave * 2 + g) * 16;
            glds16(Bt + (long)(n0 + R0 + brow) * 512 + k0 + bgs * 8,
                   &Bs[b][R0][0]);
        }
    };

    stage(0, 0);
    __syncthreads();
    for (int t = 0; t < 16; ++t) {
        const int b = t & 1;
        if (t < 15) stage(b ^ 1, (t + 1) * 32);

        f16x8 af[4], bf[4];
        #pragma unroll
        for (int i = 0; i < 4; ++i) {
            const int r  = wr * 64 + i * 16 + l16;
            const int ga = (quad * 2 + (r & 7)) & 7;
            const int gb = (quad * 2 + 1 + (r & 7)) & 7;
            const f32x4 a0 = *(const f32x4*)&Asf[b][r][ga * 4];
            const f32x4 a1 = *(const f32x4*)&Asf[b][r][gb * 4];
            f16x8 v;
            v[0] = (f16)a0[0]; v[1] = (f16)a0[1];
            v[2] = (f16)a0[2]; v[3] = (f16)a0[3];
            v[4] = (f16)a1[0]; v[5] = (f16)a1[1];
            v[6] = (f16)a1[2]; v[7] = (f16)a1[3];
            af[i] = v;
        }
        #pragma unroll
        for (int j = 0; j < 4; ++j) {
            const int r  = wc * 64 + j * 16 + l16;
            const int gp = (quad + (r & 3)) & 3;
            bf[j] = *(const f16x8*)&Bs[b][r][gp * 8];
        }
        #pragma unroll
        for (int i = 0; i < 4; ++i)
            #pragma unroll
            for (int j = 0; j < 4; ++j)
                acc[i][j] = __builtin_amdgcn_mfma_f32_16x16x32_f16(
                    af[i], bf[j], acc[i][j], 0, 0, 0);

        if (t < 15) __syncthreads();
    }

    f16* qout = (which == 0) ? qh : kh;
    #pragma unroll
    for (int i = 0; i < 4; ++i) {
        #pragma unroll
        for (int j = 0; j < 4; ++j) {
            const int col = n0 + wc * 64 + j * 16 + l16;
            const float bv = bias[col];
            #pragma unroll
            for (int r = 0; r < 4; ++r) {
                const int row = m0 + wr * 64 + i * 16 + quad * 4 + r;
                const float val = acc[i][j][r] + bv;
                if (which == 2)
                    vT[(long)(row >> 8) * 131072 + (long)col * 256 + (row & 255)] = (f16)val;
                else
                    qout[(long)row * 512 + col] = (f16)val;
            }
        }
    }
}

// ---------------- output projection: 1024 blocks x 256 threads ------------
// out[m][n] = sum_k ao[m][k] * wo[n][k] + bo[n], fp32 out. BK=32, dbuf.
__global__ __launch_bounds__(256)
void gemm_out(const f16* __restrict__ Ah, const f16* __restrict__ Bt,
              const float* __restrict__ bias, float* __restrict__ C)
{
    __shared__ __align__(16) f16 As[2][128][32];
    __shared__ __align__(16) f16 Bs[2][128][32];

    const int p    = blockIdx.x;
    const int xcd  = p & 7;
    const int slot = p >> 3;
    const int m0 = (xcd + 8 * (slot >> 2)) * 128;
    const int n0 = (slot & 3) * 128;

    const int tid  = threadIdx.x;
    const int lane = tid & 63;
    const int wave = tid >> 6;
    const int quad = lane >> 4;
    const int l16  = lane & 15;
    const int wr   = wave >> 1;
    const int wc   = wave & 1;

    f32x4 acc[4][4];
    #pragma unroll
    for (int i = 0; i < 4; ++i)
        #pragma unroll
        for (int j = 0; j < 4; ++j)
            acc[i][j] = (f32x4){0.f, 0.f, 0.f, 0.f};

    const int brow = lane >> 2;                    // 0..15
    const int bgs  = ((lane & 3) - (brow & 3)) & 3;

    auto stage = [&](int b, int k0) {
        #pragma unroll
        for (int g = 0; g < 2; ++g) {
            const int R0 = (wave * 2 + g) * 16;
            glds16(Ah + (long)(m0 + R0 + brow) * 512 + k0 + bgs * 8,
                   &As[b][R0][0]);
            glds16(Bt + (long)(n0 + R0 + brow) * 512 + k0 + bgs * 8,
                   &Bs[b][R0][0]);
        }
    };

    stage(0, 0);
    __syncthreads();
    for (int t = 0; t < 16; ++t) {
        const int b = t & 1;
        if (t < 15) stage(b ^ 1, (t + 1) * 32);

        f16x8 af[4], bf[4];
        #pragma unroll
        for (int i = 0; i < 4; ++i) {
            const int r  = wr * 64 + i * 16 + l16;
            const int ga = (quad + (r & 3)) & 3;
            af[i] = *(const f16x8*)&As[b][r][ga * 8];
        }
        #pragma unroll
        for (int j = 0; j < 4; ++j) {
            const int r  = wc * 64 + j * 16 + l16;
            const int gb = (quad + (r & 3)) & 3;
            bf[j] = *(const f16x8*)&Bs[b][r][gb * 8];
        }
        #pragma unroll
        for (int i = 0; i < 4; ++i)
            #pragma unroll
            for (int j = 0; j < 4; ++j)
                acc[i][j] = __builtin_amdgcn_mfma_f32_16x16x32_f16(
                    af[i], bf[j], acc[i][j], 0, 0, 0);

        if (t < 15) __syncthreads();
    }

    #pragma unroll
    for (int i = 0; i < 4; ++i) {
        #pragma unroll
        for (int j = 0; j < 4; ++j) {
            const int col = n0 + wc * 64 + j * 16 + l16;
            const float bv = bias[col];
            #pragma unroll
            for (int r = 0; r < 4; ++r) {
                const int row = m0 + wr * 64 + i * 16 + quad * 4 + r;
                C[(long)row * 512 + col] = acc[i][j][r] + bv;
            }
        }
    }
}

// ---------------- fused QK^T + softmax + PV, 2-phase pipelined ------------
// 256 blocks x 512 threads. LDS union (96KB big + 4KB red):
//   stage1: As2[2][128][64] @0..32K, Bs2[2][256][64] @32K..96K
//   stage2: Ps[128][256] @0..64K, Vs2[2][128][64] @64K..96K
// Transitions barrier-separated (Ps written after last QK^T read; Vs2
// region = Bs2[1], staged after softmax barriers).
__global__ __launch_bounds__(512)
void attn_fused(const f16* __restrict__ q, const f16* __restrict__ k,
                const f16* __restrict__ vT, f16* __restrict__ O)
{
    __shared__ __align__(16) f16 big[49152];        // 96 KB
    __shared__ float red[2][128][4];                //  4 KB

    f16 (*As2)[128][64] = (f16(*)[128][64])big;             // [2]
    f16 (*Bs2)[256][64] = (f16(*)[256][64])(big + 16384);   // [2]
    f16 (*Ps)[256]      = (f16(*)[256])big;                 // [128][256]
    f16 (*Vs2)[128][64] = (f16(*)[128][64])(big + 32768);   // [2]

    const int p    = blockIdx.x;
    const int xcd  = p & 7;
    const int slot = p >> 3;
    const int z    = xcd + 8 * (slot >> 1);
    const int m0   = (slot & 1) * 128;

    const int tid  = threadIdx.x;
    const int lane = tid & 63;
    const int wave = tid >> 6;
    const int quad = lane >> 4;
    const int l16  = lane & 15;
    const int wr   = wave >> 2;        // 0..1 row half
    const int wc   = wave & 3;         // 0..3 col quarter

    const f16* Aq = q  + (long)z * 131072 + (long)m0 * 512;
    const f16* Bk = k  + (long)z * 131072;
    const f16* Vt = vT + (long)z * 131072;

    f32x4 acc[4][4];
    #pragma unroll
    for (int i = 0; i < 4; ++i)
        #pragma unroll
        for (int j = 0; j < 4; ++j)
            acc[i][j] = (f32x4){0.f, 0.f, 0.f, 0.f};

    const int i8 = lane >> 3;
    const int cl = (((lane & 7) - i8) & 7) * 8;

    auto stage1 = [&](int b, int k0) {
        #pragma unroll
        for (int g = 0; g < 2; ++g) {
            const int R0 = (wave * 2 + g) * 8;
            glds16(Aq + (long)(R0 + i8) * 512 + k0 + cl, &As2[b][R0][0]);
        }
        #pragma unroll
        for (int g = 0; g < 4; ++g) {
            const int R0 = (wave * 4 + g) * 8;
            glds16(Bk + (long)(R0 + i8) * 512 + k0 + cl, &Bs2[b][R0][0]);
        }
    };

    // ---- stage 1: S = Q K^T (8 K-steps, dbuf) ----
    stage1(0, 0);
    __syncthreads();
    for (int ks = 0; ks < 8; ++ks) {
        const int b = ks & 1;
        if (ks < 7) stage1(b ^ 1, (ks + 1) * 64);

        #pragma unroll
        for (int ksub = 0; ksub < 2; ++ksub) {
            f16x8 af[4], bf[4];
            #pragma unroll
            for (int i = 0; i < 4; ++i) {
                const int r  = wr * 64 + i * 16 + l16;
                const int pc = ((ksub * 32 + quad * 8) + ((r & 7) * 8)) & 63;
                af[i] = *(const f16x8*)&As2[b][r][pc];
            }
            #pragma unroll
            for (int j = 0; j < 4; ++j) {
                const int r  = wc * 64 + j * 16 + l16;
                const int pc = ((ksub * 32 + quad * 8) + ((r & 7) * 8)) & 63;
                bf[j] = *(const f16x8*)&Bs2[b][r][pc];
            }
            #pragma unroll
            for (int i = 0; i < 4; ++i)
                #pragma unroll
                for (int j = 0; j < 4; ++j)
                    acc[i][j] = __builtin_amdgcn_mfma_f32_16x16x32_f16(
                        af[i], bf[j], acc[i][j], 0, 0, 0);
        }
        if (ks < 7) __syncthreads();
    }

    // ---- softmax (rows of 256) ----
    const float scale = 0.044194173824159216f;  // 1/sqrt(512)
    float st[4][4];
    #pragma unroll
    for (int i = 0; i < 4; ++i)
        #pragma unroll
        for (int r = 0; r < 4; ++r) {
            float m = acc[i][0][r];
            #pragma unroll
            for (int j = 1; j < 4; ++j) m = fmaxf(m, acc[i][j][r]);
            st[i][r] = m;
        }
    #pragma unroll
    for (int off = 1; off < 16; off <<= 1)
        #pragma unroll
        for (int i = 0; i < 4; ++i)
            #pragma unroll
            for (int r = 0; r < 4; ++r)
                st[i][r] = fmaxf(st[i][r], __shfl_xor(st[i][r], off, 64));
    if (l16 == 0)
        #pragma unroll
        for (int i = 0; i < 4; ++i)
            #pragma unroll
            for (int r = 0; r < 4; ++r)
                red[0][wr * 64 + i * 16 + quad * 4 + r][wc] = st[i][r];
    __syncthreads();   // all QK^T LDS reads done -> big reusable as Ps

    // exp (unnormalized, e<=1) -> Ps (swizzled); local sums
    #pragma unroll
    for (int i = 0; i < 4; ++i)
        #pragma unroll
        for (int r = 0; r < 4; ++r) {
            const int row = wr * 64 + i * 16 + quad * 4 + r;
            const float m = fmaxf(fmaxf(red[0][row][0], red[0][row][1]),
                                  fmaxf(red[0][row][2], red[0][row][3]));
            float s = 0.f;
            #pragma unroll
            for (int j = 0; j < 4; ++j) {
                const float e = __expf(scale * (acc[i][j][r] - m));
                s += e;
                const int col = wc * 64 + j * 16 + l16;
                Ps[row][(col & 192) + (((col & 63) + ((row & 7) * 8)) & 63)] = (f16)e;
            }
            st[i][r] = s;
        }
    #pragma unroll
    for (int off = 1; off < 16; off <<= 1)
        #pragma unroll
        for (int i = 0; i < 4; ++i)
            #pragma unroll
            for (int r = 0; r < 4; ++r)
                st[i][r] += __shfl_xor(st[i][r], off, 64);
    if (l16 == 0)
        #pragma unroll
        for (int i = 0; i < 4; ++i)
            #pragma unroll
            for (int r = 0; r < 4; ++r)
                red[1][wr * 64 + i * 16 + quad * 4 + r][wc] = st[i][r];
    __syncthreads();

    if (tid < 128) {
        const float s = red[1][tid][0] + red[1][tid][1] +
                        red[1][tid][2] + red[1][tid][3];
        red[0][tid][0] = 1.0f / s;
    }

    // ---- stage 2: O = P V, flattened (nc,kb) with kb-granular V dbuf ----
    auto stageV = [&](int b, int it) {
        const int nc = it >> 2, kb = it & 3;
        #pragma unroll
        for (int g = 0; g < 2; ++g) {
            const int R0 = (wave * 2 + g) * 8;
            glds16(Vt + (long)(nc * 128 + R0 + i8) * 256 + kb * 64 + cl,
                   &Vs2[b][R0][0]);
        }
    };

    stageV(0, 0);
    __syncthreads();   // drains V(0); publishes inv (written above)

    f32x4 acc2[4][2];
    for (int it = 0; it < 16; ++it) {
        const int b  = it & 1;
        const int nc = it >> 2;
        const int kb = it & 3;
        if (it < 15) stageV(b ^ 1, it + 1);

        if (kb == 0) {
            #pragma unroll
            for (int i = 0; i < 4; ++i)
                #pragma unroll
                for (int j = 0; j < 2; ++j)
                    acc2[i][j] = (f32x4){0.f, 0.f, 0.f, 0.f};
        }

        #pragma unroll
        for (int ksub = 0; ksub < 2; ++ksub) {
            f16x8 af[4], bf[2];
            #pragma unroll
            for (int i = 0; i < 4; ++i) {
                const int r  = wr * 64 + i * 16 + l16;
                const int pc = kb * 64 +
                    (((ksub * 32 + quad * 8) + ((r & 7) * 8)) & 63);
                af[i] = *(const f16x8*)&Ps[r][pc];
            }
            #pragma unroll
            for (int j = 0; j < 2; ++j) {
                const int rv = wc * 32 + j * 16 + l16;
                const int pc = ((ksub * 32 + quad * 8) + ((rv & 7) * 8)) & 63;
                bf[j] = *(const f16x8*)&Vs2[b][rv][pc];
            }
            #pragma unroll
            for (int i = 0; i < 4; ++i)
                #pragma unroll
                for (int j = 0; j < 2; ++j)
                    acc2[i][j] = __builtin_amdgcn_mfma_f32_16x16x32_f16(
                        af[i], bf[j], acc2[i][j], 0, 0, 0);
        }

        if (kb == 3) {
            #pragma unroll
            for (int i = 0; i < 4; ++i)
                #pragma unroll
                for (int j = 0; j < 2; ++j) {
                    const int col = nc * 128 + wc * 32 + j * 16 + l16;
                    #pragma unroll
                    for (int rr = 0; rr < 4; ++rr) {
                        const int row = wr * 64 + i * 16 + quad * 4 + rr;
                        const float inv = red[0][row][0];
                        O[(long)z * 131072 + (long)(m0 + row) * 512 + col] =
                            (f16)(acc2[i][j][rr] * inv);
                    }
                }
        }
        if (it < 15) __syncthreads();
    }
}

__global__ __launch_bounds__(256)
void cvt3(const float* __restrict__ a, const float* __restrict__ b,
          const float* __restrict__ c, f16* __restrict__ oa,
          f16* __restrict__ ob, f16* __restrict__ oc)
{
    const int w = blockIdx.x >> 8;
    const int t = ((blockIdx.x & 255) * 256 + threadIdx.x) * 4;
    const float* src = (w == 0) ? a : (w == 1) ? b : c;
    f16* dst = (w == 0) ? oa : (w == 1) ? ob : oc;
    const float4 v = *(const float4*)(src + t);
    f16x4 o;
    o[0] = (f16)v.x; o[1] = (f16)v.y; o[2] = (f16)v.z; o[3] = (f16)v.w;
    *(f16x4*)(dst + t) = o;
}

extern "C" void kernel_launch(void* const* d_in, const int* in_sizes, int n_in,
                              void* d_out, int out_size, void* d_ws, size_t ws_size,
                              hipStream_t stream)
{
    const float* queries = (const float*)d_in[0];
    const float* keys    = (const float*)d_in[1];
    const float* values  = (const float*)d_in[2];
    const float* Wq      = (const float*)d_in[3];
    const float* bq      = (const float*)d_in[4];
    const float* Wkv     = (const float*)d_in[5];
    const float* bkv     = (const float*)d_in[6];
    const float* Wo      = (const float*)d_in[7];
    const float* bo      = (const float*)d_in[8];
    float* out = (float*)d_out;

    // f16 workspace layout (~96 MB + weights):
    f16* ws  = (f16*)d_ws;
    f16* wq  = ws;                      //   262144
    f16* wkv = ws + 262144;
    f16* wo  = ws + 524288;
    f16* qh  = ws + 786432;             // 32 MB  q  (ao overlays after attn)
    f16* kh  = qh + 16777216;           // 32 MB  k
    f16* vT  = kh + 16777216;           // 32 MB  v^T
    f16* ao  = qh;                      // overlay: block writes only rows it
                                        // alone reads, after its last read

    cvt3<<<768, 256, 0, stream>>>(Wq, Wkv, Wo, wq, wkv, wo);

    proj3<<<3072, dim3(256), 0, stream>>>(
        queries, keys, values, wq, wkv, bq, bkv, qh, kh, vT);

    attn_fused<<<256, 512, 0, stream>>>(qh, kh, vT, ao);

    gemm_out<<<1024, dim3(256), 0, stream>>>(ao, wo, bo, out);
}